// Round 1
// baseline (318.934 us; speedup 1.0000x reference)
//
#include <hip/hip_runtime.h>
#include <hip/hip_bf16.h>
#include <math.h>

// Problem constants (fixed by setup_inputs)
#define S3    128
#define NB    2
#define CF    16
#define CHS   (S3*S3*S3)          // 2097152 = 2^21 (per-channel voxel count)
#define NVOX  (NB*CHS)            // 4194304
#define NW    (NVOX/64)           // 65536 bit-words
#define NROWS (NB*S3*S3)          // 32768 rows along W

typedef unsigned long long u64;
typedef unsigned int u32;

// ---- workspace layout (bytes) ----
#define ACC_OFF    0              // double[64] accumulators
#define STD_OFF    512            // float[16] std_n
#define SCAN_OFF   576            // u32[32] scan scalars (incl. eq counter at [7])
#define HISTA_OFF  1024           // u32[4096]
#define HISTB_OFF  17408          // u32[4096]
#define HISTC_OFF  33792          // u32[256]
#define EQ_OFF     34816          // u32[4096] equal-key voxel indices
#define ZERO_BYTES 51200
#define POSB_OFF   65536
#define MASKB      (NW*8)         // 524288 bytes per bitmask
#define NEGB_OFF   (POSB_OFF + 1*MASKB)
#define HIB_OFF    (POSB_OFF + 2*MASKB)
#define TMP1_OFF   (POSB_OFF + 3*MASKB)
#define TMP2_OFF   (POSB_OFF + 4*MASKB)
#define DILP_OFF   (POSB_OFF + 5*MASKB)
#define DILH_OFF   (POSB_OFF + 6*MASKB)
#define COS_OFF    (POSB_OFF + 7*MASKB)   // float[NVOX] = 16.8 MB

// accumulator indices (doubles)
// 0..15 pos feature sums; 17 ce_sum; 18..20 S_c; 21..23 T_c; 24..26 N_c
// 27 s_pos; 28 s_easy; 29 c_easy; 30 s_fneg; 31 c_fneg

__device__ __forceinline__ double wave_red(double x) {
    for (int o = 32; o > 0; o >>= 1) x += __shfl_down(x, o);
    return x;
}

__device__ __forceinline__ u32 mono_key(float f) {
    u32 u = __float_as_uint(f);
    return (u & 0x80000000u) ? ~u : (u | 0x80000000u);
}

// ---- pass 1: target stats, pos/neg bitmasks, pos-feature channel sums ----
__global__ __launch_bounds__(256) void k_prep(const float* __restrict__ feat,
        const int* __restrict__ tgt, u64* __restrict__ posb, u64* __restrict__ negb,
        double* __restrict__ acc)
{
    int tid = blockIdx.x * 256 + threadIdx.x;
    const int stride = gridDim.x * 256;
    double fs[CF];
    #pragma unroll
    for (int c = 0; c < CF; c++) fs[c] = 0.0;
    double n0 = 0, n1 = 0, n2 = 0;
    for (int v = tid; v < NVOX; v += stride) {
        int t = tgt[v];
        bool pos = (t == 1);
        u64 bp = __ballot(pos);
        u64 bn = __ballot(t == 0);
        if ((threadIdx.x & 63) == 0) { posb[v >> 6] = bp; negb[v >> 6] = bn; }
        n0 += (t == 0) ? 1.0 : 0.0;
        n1 += pos ? 1.0 : 0.0;
        n2 += (t == 2) ? 1.0 : 0.0;
        if (pos) {
            const float* fb = feat + (size_t)(v >> 21) * ((size_t)(CF - 1) * CHS) + v;
            #pragma unroll
            for (int c = 0; c < CF; c++) fs[c] += (double)fb[(size_t)c * CHS];
        }
    }
    __shared__ double red[4][19];
    int lane = threadIdx.x & 63, wid = threadIdx.x >> 6;
    double vals[19];
    #pragma unroll
    for (int c = 0; c < 16; c++) vals[c] = fs[c];
    vals[16] = n0; vals[17] = n1; vals[18] = n2;
    #pragma unroll
    for (int i = 0; i < 19; i++) {
        double x = wave_red(vals[i]);
        if (lane == 0) red[wid][i] = x;
    }
    __syncthreads();
    if (threadIdx.x < 19) {
        double s = red[0][threadIdx.x] + red[1][threadIdx.x] + red[2][threadIdx.x] + red[3][threadIdx.x];
        int dst = threadIdx.x < 16 ? threadIdx.x : (24 + (threadIdx.x - 16));
        atomicAdd(&acc[dst], s);
    }
}

// ---- CE + dice sums over net_output ----
__global__ __launch_bounds__(256) void k_ce(const float* __restrict__ net,
        const int* __restrict__ tgt, double* __restrict__ acc)
{
    int tid = blockIdx.x * 256 + threadIdx.x;
    const int stride = gridDim.x * 256;
    double ce = 0, s0 = 0, s1 = 0, s2 = 0, t0 = 0, t1 = 0, t2 = 0;
    for (int v = tid; v < NVOX; v += stride) {
        size_t base = (size_t)v + (size_t)(v >> 21) * (2 * (size_t)CHS);
        float x0 = net[base], x1 = net[base + CHS], x2 = net[base + 2 * (size_t)CHS];
        float m = fmaxf(x0, fmaxf(x1, x2));
        float e0 = expf(x0 - m), e1 = expf(x1 - m), e2 = expf(x2 - m);
        float sum = e0 + e1 + e2;
        float lse = m + logf(sum);
        int t = tgt[v];
        float xt = (t == 0) ? x0 : ((t == 1) ? x1 : x2);
        ce += (double)(lse - xt);
        float inv = 1.0f / sum;
        float p0 = e0 * inv, p1 = e1 * inv, p2 = e2 * inv;
        s0 += p0; s1 += p1; s2 += p2;
        if (t == 0) t0 += p0; else if (t == 1) t1 += p1; else t2 += p2;
    }
    __shared__ double red[4][7];
    int lane = threadIdx.x & 63, wid = threadIdx.x >> 6;
    double vals[7] = {ce, s0, s1, s2, t0, t1, t2};
    #pragma unroll
    for (int i = 0; i < 7; i++) {
        double x = wave_red(vals[i]);
        if (lane == 0) red[wid][i] = x;
    }
    __syncthreads();
    if (threadIdx.x < 7) {
        double s = red[0][threadIdx.x] + red[1][threadIdx.x] + red[2][threadIdx.x] + red[3][threadIdx.x];
        atomicAdd(&acc[17 + threadIdx.x], s);
    }
}

// ---- std_n from pos-feature sums ----
__global__ void k_std(const double* __restrict__ acc, float* __restrict__ stdn) {
    __shared__ float v[16];
    double cnt = acc[25];
    if (threadIdx.x < 16) {
        double mp = acc[threadIdx.x] / fmax(cnt, 1.0);
        v[threadIdx.x] = (cnt > 0.0) ? (float)mp : 0.0f;
    }
    __syncthreads();
    if (threadIdx.x == 0) {
        float n = 0;
        for (int c = 0; c < 16; c++) n += v[c] * v[c];
        n = fmaxf(sqrtf(n), 1e-12f);
        for (int c = 0; c < 16; c++) stdn[c] = v[c] / n;
    }
}

// ---- pass 2: cos_map + level-A histogram (top 12 bits of monotonic key) ----
__global__ __launch_bounds__(256) void k_cos(const float* __restrict__ feat,
        const float* __restrict__ stdn, const u64* __restrict__ negb,
        float* __restrict__ cosm, u32* __restrict__ histA)
{
    __shared__ u32 h[4096];
    __shared__ float sn[16];
    for (int i = threadIdx.x; i < 4096; i += 256) h[i] = 0;
    if (threadIdx.x < 16) sn[threadIdx.x] = stdn[threadIdx.x];
    __syncthreads();
    int tid = blockIdx.x * 256 + threadIdx.x;
    const int stride = gridDim.x * 256;
    int lane = threadIdx.x & 63;
    for (int v = tid; v < NVOX; v += stride) {
        const float* fb = feat + (size_t)(v >> 21) * ((size_t)(CF - 1) * CHS) + v;
        float dot = 0, nn = 0;
        #pragma unroll
        for (int c = 0; c < CF; c++) {
            float x = fb[(size_t)c * CHS];
            dot = fmaf(x, sn[c], dot);
            nn = fmaf(x, x, nn);
        }
        float cs = dot / fmaxf(sqrtf(nn), 1e-12f);
        cosm[v] = cs;
        u64 nw = negb[v >> 6];
        if ((nw >> lane) & 1ull) atomicAdd(&h[mono_key(cs) >> 20], 1u);
    }
    __syncthreads();
    for (int i = threadIdx.x; i < 4096; i += 256)
        if (h[i]) atomicAdd(&histA[i], h[i]);
}

// ---- descending-bin scan: find boundary bin + residual need ----
__global__ void k_scan(const u32* __restrict__ hist, int nbins,
                       const u32* __restrict__ needPtr, u32* outBin, u32* outNeed)
{
    __shared__ u32 cs[256];
    int per = nbins / 256;
    u32 s = 0;
    for (int j = 0; j < per; j++) s += hist[threadIdx.x * per + j];
    cs[threadIdx.x] = s;
    __syncthreads();
    if (threadIdx.x == 0) {
        u32 need = needPtr ? *needPtr : 250u;
        u32 cum = 0; int chunk = 0;
        for (int c = 255; c >= 0; c--) {
            if (cum + cs[c] >= need) { chunk = c; break; }
            cum += cs[c];
        }
        int bin = chunk * per;
        for (int b = chunk * per + per - 1; b >= chunk * per; b--) {
            if (cum + hist[b] >= need) { bin = b; break; }
            cum += hist[b];
        }
        *outBin = (u32)bin;
        *outNeed = need - cum;
    }
}

// ---- histogram refinement (level 1: bits 8..19 within binA; level 2: bits 0..7 within prefix24) ----
__global__ __launch_bounds__(256) void k_hist_refine(const float* __restrict__ cosm,
        const u64* __restrict__ negb, const u32* __restrict__ scan,
        u32* __restrict__ hist, int level)
{
    int tid = blockIdx.x * 256 + threadIdx.x;
    const int stride = gridDim.x * 256;
    int lane = threadIdx.x & 63;
    u32 binA = scan[0];
    u32 pre24 = (scan[0] << 12) | scan[2];
    for (int v = tid; v < NVOX; v += stride) {
        u64 nw = negb[v >> 6];
        if (!((nw >> lane) & 1ull)) continue;
        u32 key = mono_key(cosm[v]);
        if (level == 1) {
            if ((key >> 20) == binA) atomicAdd(&hist[(key >> 8) & 0xFFFu], 1u);
        } else {
            if ((key >> 8) == pre24) atomicAdd(&hist[key & 0xFFu], 1u);
        }
    }
}

// ---- mark strictly-greater keys into hi bitmask; collect equal-key indices ----
__global__ __launch_bounds__(256) void k_mark(const float* __restrict__ cosm,
        const u64* __restrict__ negb, u64* __restrict__ hib,
        u32* __restrict__ scan, u32* __restrict__ eqbuf)
{
    int tid = blockIdx.x * 256 + threadIdx.x;
    const int stride = gridDim.x * 256;
    int lane = threadIdx.x & 63;
    u32 K250 = (scan[0] << 20) | (scan[2] << 8) | scan[8];
    for (int v = tid; v < NVOX; v += stride) {
        u64 nw = negb[v >> 6];
        bool neg = (nw >> lane) & 1ull;
        u32 key = neg ? mono_key(cosm[v]) : 0u;
        bool gt = neg && (key > K250);
        u64 b = __ballot(gt);
        if (lane == 0) hib[v >> 6] = b;
        if (neg && key == K250) {
            u32 p = atomicAdd(&scan[7], 1u);
            if (p < 4096) eqbuf[p] = (u32)v;
        }
    }
}

// ---- mark the lowest-index equal-key voxels (tie handling, matches lax.top_k) ----
__global__ void k_markeq(u32* __restrict__ scan, const u32* __restrict__ eqbuf,
                         u64* __restrict__ hib)
{
    if (threadIdx.x != 0 || blockIdx.x != 0) return;
    int need = (int)scan[9];
    int n = (int)scan[7]; if (n > 4096) n = 4096;
    u32 prev = 0; bool first = true;
    for (int k = 0; k < need; k++) {
        u32 best = 0xFFFFFFFFu;
        for (int i = 0; i < n; i++) {
            u32 x = eqbuf[i];
            if ((first || x > prev) && x < best) best = x;
        }
        if (best == 0xFFFFFFFFu) break;
        atomicOr(&hib[best >> 6], 1ull << (best & 63));
        prev = best; first = false;
    }
}

// ---- separable box dilation on bitmasks ----
__global__ void k_dilW(const u64* __restrict__ in, u64* __restrict__ out) {
    int r = blockIdx.x * 256 + threadIdx.x;
    if (r >= NROWS) return;
    u64 lo = in[2 * r], hi = in[2 * r + 1];
    u64 rl = lo, rh = hi;
    #pragma unroll
    for (int s = 1; s <= 10; s++) {
        rl |= (lo << s) | (lo >> s) | (hi << (64 - s));
        rh |= (hi << s) | (hi >> s) | (lo >> (64 - s));
    }
    out[2 * r] = rl; out[2 * r + 1] = rh;
}

__global__ void k_dilH(const u64* __restrict__ in, u64* __restrict__ out) {
    int n = blockIdx.x * 256 + threadIdx.x;
    if (n >= NW) return;
    int h = (n >> 1) & 127;
    int base = n - (h << 1);
    int lo = h > 10 ? h - 10 : 0;
    int hi2 = h + 10 > 127 ? 127 : h + 10;
    u64 r = 0;
    for (int j = lo; j <= hi2; j++) r |= in[base + (j << 1)];
    out[n] = r;
}

__global__ void k_dilD(const u64* __restrict__ in, u64* __restrict__ out) {
    int n = blockIdx.x * 256 + threadIdx.x;
    if (n >= NW) return;
    int d = (n >> 8) & 127;
    int base = n - (d << 8);
    int lo = d > 10 ? d - 10 : 0;
    int hi2 = d + 10 > 127 ? 127 : d + 10;
    u64 r = 0;
    for (int j = lo; j <= hi2; j++) r |= in[base + (j << 8)];
    out[n] = r;
}

// ---- final masked sums over cos_map ----
__global__ __launch_bounds__(256) void k_fin(const float* __restrict__ cosm,
        const u64* __restrict__ posb, const u64* __restrict__ dilp,
        const u64* __restrict__ dilh, double* __restrict__ acc)
{
    int tid = blockIdx.x * 256 + threadIdx.x;
    const int stride = gridDim.x * 256;
    int lane = threadIdx.x & 63;
    double sp = 0, se = 0, cej = 0, sf = 0, cf = 0;
    for (int v = tid; v < NVOX; v += stride) {
        int w = v >> 6;
        u64 pb = posb[w];
        u64 easyw = dilp[w] & ~pb;
        u64 fnw = dilh[w] & ~pb;
        bool p = (pb >> lane) & 1ull;
        bool ez = (easyw >> lane) & 1ull;
        bool fn = (fnw >> lane) & 1ull;
        if (p | ez | fn) {
            float cs = cosm[v];
            float rl = fmaxf(cs, 0.0f);
            if (p) sp += (double)(1.0f - cs);
            if (ez) { se += (double)rl; cej += 1.0; }
            if (fn) { sf += (double)rl; cf += 1.0; }
        }
    }
    __shared__ double red[4][5];
    int wid = threadIdx.x >> 6;
    double vals[5] = {sp, se, cej, sf, cf};
    #pragma unroll
    for (int i = 0; i < 5; i++) {
        double x = wave_red(vals[i]);
        if (lane == 0) red[wid][i] = x;
    }
    __syncthreads();
    if (threadIdx.x < 5) {
        double s = red[0][threadIdx.x] + red[1][threadIdx.x] + red[2][threadIdx.x] + red[3][threadIdx.x];
        atomicAdd(&acc[27 + threadIdx.x], s);
    }
}

// ---- combine everything into the scalar loss ----
__global__ void k_combine(const double* __restrict__ acc, float* __restrict__ out) {
    if (threadIdx.x != 0 || blockIdx.x != 0) return;
    double ce = acc[17] / (double)NVOX;
    double dcl = 0;
    for (int c = 1; c <= 2; c++) {
        double T = acc[21 + c], Sx = acc[18 + c], N = acc[24 + c];
        double dc = (2.0 * T + 1e-5) / fmax(Sx + N + 1e-5, 1e-8);
        dcl += dc;
    }
    double dc_loss = -(dcl / 2.0);
    double cp = acc[25];
    double pl = (cp > 0.0) ? acc[27] / fmax(cp, 1.0) : 0.0;
    double ml = (acc[29] > 0.0) ? acc[28] / acc[29] : 0.0;
    double nl = (acc[31] > 0.0) ? acc[30] / acc[31] : 0.0;
    out[0] = (float)(ce + dc_loss + 5.0 * (pl + ml + nl));
}

extern "C" void kernel_launch(void* const* d_in, const int* in_sizes, int n_in,
                              void* d_out, int out_size, void* d_ws, size_t ws_size,
                              hipStream_t stream)
{
    const float* feat = (const float*)d_in[0];
    const float* net  = (const float*)d_in[1];
    const int*   tgt  = (const int*)d_in[2];
    float* out = (float*)d_out;
    char* w = (char*)d_ws;

    double* acc  = (double*)(w + ACC_OFF);
    float* stdn  = (float*)(w + STD_OFF);
    u32* scan    = (u32*)(w + SCAN_OFF);
    u32* histA   = (u32*)(w + HISTA_OFF);
    u32* histB   = (u32*)(w + HISTB_OFF);
    u32* histC   = (u32*)(w + HISTC_OFF);
    u32* eqbuf   = (u32*)(w + EQ_OFF);
    u64* posb    = (u64*)(w + POSB_OFF);
    u64* negb    = (u64*)(w + NEGB_OFF);
    u64* hib     = (u64*)(w + HIB_OFF);
    u64* tmp1    = (u64*)(w + TMP1_OFF);
    u64* tmp2    = (u64*)(w + TMP2_OFF);
    u64* dilp    = (u64*)(w + DILP_OFF);
    u64* dilh    = (u64*)(w + DILH_OFF);
    float* cosm  = (float*)(w + COS_OFF);

    hipMemsetAsync(w, 0, ZERO_BYTES, stream);

    k_prep<<<2048, 256, 0, stream>>>(feat, tgt, posb, negb, acc);
    k_ce<<<2048, 256, 0, stream>>>(net, tgt, acc);
    k_std<<<1, 64, 0, stream>>>(acc, stdn);
    k_cos<<<2048, 256, 0, stream>>>(feat, stdn, negb, cosm, histA);
    k_scan<<<1, 256, 0, stream>>>(histA, 4096, (const u32*)nullptr, &scan[0], &scan[1]);
    k_hist_refine<<<2048, 256, 0, stream>>>(cosm, negb, scan, histB, 1);
    k_scan<<<1, 256, 0, stream>>>(histB, 4096, &scan[1], &scan[2], &scan[3]);
    k_hist_refine<<<2048, 256, 0, stream>>>(cosm, negb, scan, histC, 2);
    k_scan<<<1, 256, 0, stream>>>(histC, 256, &scan[3], &scan[8], &scan[9]);
    k_mark<<<2048, 256, 0, stream>>>(cosm, negb, hib, scan, eqbuf);
    k_markeq<<<1, 64, 0, stream>>>(scan, eqbuf, hib);

    // dilate pos -> dilp
    k_dilW<<<NROWS / 256, 256, 0, stream>>>(posb, tmp1);
    k_dilH<<<NW / 256, 256, 0, stream>>>(tmp1, tmp2);
    k_dilD<<<NW / 256, 256, 0, stream>>>(tmp2, dilp);
    // dilate hi -> dilh
    k_dilW<<<NROWS / 256, 256, 0, stream>>>(hib, tmp1);
    k_dilH<<<NW / 256, 256, 0, stream>>>(tmp1, tmp2);
    k_dilD<<<NW / 256, 256, 0, stream>>>(tmp2, dilh);

    k_fin<<<2048, 256, 0, stream>>>(cosm, posb, dilp, dilh, acc);
    k_combine<<<1, 64, 0, stream>>>(acc, out);
}